// Round 9
// baseline (28.581 us; speedup 1.0000x reference)
//
#include <hip/hip_runtime.h>
#include <hip/hip_bf16.h>

#define L2E 1.4426950408889634f

typedef float    f32x2 __attribute__((ext_vector_type(2)));
typedef int      i32x2 __attribute__((ext_vector_type(2)));
typedef unsigned u32x2 __attribute__((ext_vector_type(2)));

__device__ __forceinline__ f32x2 pk_fma(f32x2 a, f32x2 b, f32x2 c) {
    return __builtin_elementwise_fma(a, b, c);
}

// Packed full-rate-VALU sigmoid pair. Input pre-scaled: y = -log2(e)*x.
// Returns sigma(x) = 1/(1 + 2^y) for both halves.
//   2^y: Schraudolph split -- t = RNE(y + 1.5*2^23) => k in low mantissa
//        bits; scale = bits(t)<<23 + 0x3F800000 = 2^k exactly; f = y - k in
//        [-0.5,0.5]; 2^f by deg-3 Taylor (rel err ~6e-4 -> sigma abs err
//        <= 1.5e-4). No rndne/cvt/ldexp.
//   1/(1+e): magic-constant guess + 2 Newton iterations (rel err ~1e-6).
// All float ops are <2 x float> so the backend can form V_PK_FMA_F32 /
// V_PK_MUL_F32 / V_PK_ADD_F32 (full-rate packed FP32, CDNA3+): both
// elements of the thread ride one instruction. Rounds 1-8 measured:
// trans ~32 cyc/wave64, LDS gather ~11 cyc, VALU 2 cyc -- so the only
// path below the 22 us wall is fewer VALU issues, i.e. packing.
__device__ __forceinline__ f32x2 sig2(f32x2 y) {
    const f32x2 magic = 12582912.0f;          // 1.5 * 2^23
    const f32x2 t  = y + magic;               // RNE -> magic + k (exact)
    const f32x2 kf = t - magic;               // k as float (exact)
    const f32x2 f  = y - kf;                  // [-0.5, 0.5]
    const i32x2 bt = __builtin_bit_cast(i32x2, t);
    const f32x2 scale = __builtin_bit_cast(f32x2, (bt << 23) + 0x3F800000); // 2^k
    f32x2 p = pk_fma(f, (f32x2)0.0555041f, (f32x2)0.2402265f);
    p = pk_fma(f, p, (f32x2)0.6931472f);
    p = pk_fma(f, p, (f32x2)1.0f);            // 2^f
    const f32x2 den = pk_fma(p, scale, (f32x2)1.0f);   // 1 + 2^y
    const u32x2 gb = (u32x2)0x7EF127EAu - __builtin_bit_cast(u32x2, den);
    f32x2 g = __builtin_bit_cast(f32x2, gb);
    g = g * pk_fma(-den, g, (f32x2)2.0f);
    g = g * pk_fma(-den, g, (f32x2)2.0f);
    return g;
}

__global__ __launch_bounds__(256) void lstm_fc_v9(
    const float4* __restrict__ x4,     // [B] float4 (SEQ=4, INPUT=1)
    const float*  __restrict__ W_ih,   // [8]
    const float*  __restrict__ W_hh,   // [8,2]
    const float*  __restrict__ b_ih,   // [8]
    const float*  __restrict__ b_hh,   // [8]
    const float*  __restrict__ W_fc,   // [1,2]
    const float*  __restrict__ b_fc,   // [1]
    float* __restrict__ out,           // [B]
    int B)
{
    // Pre-scaled weights (uniform): y_gate = -L2E*gate (i,f,o) and
    // -2*L2E*gate (g, since tanh(g) = 2*sigma(2g) - 1).
    // Gate order [i,f,g,o] x H=2: 0,1=i  2,3=f  4,5=g  6,7=o.
    f32x2 ws[8], w0[8], w1[8], bb[8];
#pragma unroll
    for (int g = 0; g < 8; ++g) {
        const float s = (g == 4 || g == 5) ? (-2.0f * L2E) : (-L2E);
        ws[g] = (f32x2)(s * W_ih[g]);
        w0[g] = (f32x2)(s * W_hh[2 * g]);
        w1[g] = (f32x2)(s * W_hh[2 * g + 1]);
        bb[g] = (f32x2)(s * (b_ih[g] + b_hh[g]));
    }
    const float wfc0 = W_fc[0], wfc1 = W_fc[1], bfc = b_fc[0];
    // d-state pre-scaled: d = -L2E*2c, so sig2(d) = sigma(2c) and
    // tanh(c) = 2*sigma(2c) - 1.  d = f*d + i*u, u = 2*L2E - 4*L2E*sig(2g).
    const f32x2 U_A = (f32x2)(-4.0f * L2E), U_B = (f32x2)(2.0f * L2E);

    const int half = B >> 1;
    const int tid = blockIdx.x * blockDim.x + threadIdx.x;
    if (tid >= half) return;

    // Two elements per thread, PACKED as the two halves of every f32x2.
    const float4 xa = x4[tid];
    const float4 xb = x4[tid + half];
    f32x2 xv[4];
    xv[0] = (f32x2){xa.x, xb.x};
    xv[1] = (f32x2){xa.y, xb.y};
    xv[2] = (f32x2){xa.z, xb.z};
    xv[3] = (f32x2){xa.w, xb.w};

    f32x2 h0, h1, d0, d1;

    // ---- t = 0 (h = c = 0): f unused ----
    {
        const f32x2 si0 = sig2(pk_fma(ws[0], xv[0], bb[0]));
        const f32x2 si1 = sig2(pk_fma(ws[1], xv[0], bb[1]));
        const f32x2 sg0 = sig2(pk_fma(ws[4], xv[0], bb[4]));
        const f32x2 sg1 = sig2(pk_fma(ws[5], xv[0], bb[5]));
        const f32x2 so0 = sig2(pk_fma(ws[6], xv[0], bb[6]));
        const f32x2 so1 = sig2(pk_fma(ws[7], xv[0], bb[7]));
        d0 = si0 * pk_fma(U_A, sg0, U_B);
        d1 = si1 * pk_fma(U_A, sg1, U_B);
        const f32x2 sd0 = sig2(d0);
        const f32x2 sd1 = sig2(d1);
        h0 = pk_fma((f32x2)2.0f, so0 * sd0, -so0);   // o*(2*sigma(2c)-1)
        h1 = pk_fma((f32x2)2.0f, so1 * sd1, -so1);
    }

    // ---- t = 1..3 ----
#pragma unroll
    for (int t = 1; t < 4; ++t) {
        f32x2 y[8];
#pragma unroll
        for (int g = 0; g < 8; ++g)
            y[g] = pk_fma(ws[g], xv[t],
                   pk_fma(w0[g], h0,
                   pk_fma(w1[g], h1, bb[g])));
        const f32x2 si0 = sig2(y[0]);
        const f32x2 si1 = sig2(y[1]);
        const f32x2 sf0 = sig2(y[2]);
        const f32x2 sf1 = sig2(y[3]);
        const f32x2 sg0 = sig2(y[4]);
        const f32x2 sg1 = sig2(y[5]);
        const f32x2 so0 = sig2(y[6]);
        const f32x2 so1 = sig2(y[7]);
        d0 = pk_fma(sf0, d0, si0 * pk_fma(U_A, sg0, U_B));
        d1 = pk_fma(sf1, d1, si1 * pk_fma(U_A, sg1, U_B));
        const f32x2 sd0 = sig2(d0);
        const f32x2 sd1 = sig2(d1);
        h0 = pk_fma((f32x2)2.0f, so0 * sd0, -so0);
        h1 = pk_fma((f32x2)2.0f, so1 * sd1, -so1);
    }

    out[tid]        = fmaf(wfc0, h0.x, fmaf(wfc1, h1.x, bfc));
    out[tid + half] = fmaf(wfc0, h0.y, fmaf(wfc1, h1.y, bfc));
}

extern "C" void kernel_launch(void* const* d_in, const int* in_sizes, int n_in,
                              void* d_out, int out_size, void* d_ws, size_t ws_size,
                              hipStream_t stream) {
    const float4* x4   = (const float4*)d_in[0];
    const float*  W_ih = (const float*)d_in[1];
    const float*  W_hh = (const float*)d_in[2];
    const float*  b_ih = (const float*)d_in[3];
    const float*  b_hh = (const float*)d_in[4];
    const float*  W_fc = (const float*)d_in[5];
    const float*  b_fc = (const float*)d_in[6];
    float* out = (float*)d_out;

    const int B = out_size;                  // 2,097,152
    const int half = B >> 1;
    const int block = 256;
    const int grid = (half + block - 1) / block;   // 4096 blocks, 2 elems/thread
    lstm_fc_v9<<<grid, block, 0, stream>>>(x4, W_ih, W_hh, b_ih, b_hh,
                                           W_fc, b_fc, out, B);
}